// Round 10
// baseline (139.955 us; speedup 1.0000x reference)
//
#include <hip/hip_runtime.h>

#define WIRES   12
#define NSTATE  4096          // 2^12
#define QDEPTH  8
#define BLOCK   256           // 4 waves per block = one batch element
#define PER_T   16            // 4 reg bits; +2 quad-DPP lane bits = 6 wires/phase

using f2 = __attribute__((ext_vector_type(2))) float;

// Pitch-17 padded layout: amp a -> f2-slot a + (a>>4). (Proven R1/R6/R8:
// measured conflict floor 3.8M, W/R transpose rounds bank-minimum.)
__device__ __forceinline__ int slotf(int a) { return a + (a >> 4); }

// Column j of the GF(2)-linear CNOT-ring permutation of layer l:
// F = g_0∘g_1∘...∘g_11 (g_11 applied first / innermost).
constexpr int colF(int l, int j) {
    int rr = (l % (WIRES - 1)) + 1;
    int v = 1 << j;
    for (int k = WIRES - 1; k >= 0; --k) {
        int bc = 11 - k;                   // control bit
        int bt = 11 - ((k + rr) % WIRES);  // target bit
        v ^= ((v >> bc) & 1) << bt;
    }
    return v;
}
struct ColsT { int v[QDEPTH][WIRES]; };
constexpr ColsT mkCols() {
    ColsT c{};
    for (int l = 0; l < QDEPTH; ++l)
        for (int j = 0; j < WIRES; ++j) c.v[l][j] = colF(l, j);
    return c;
}
static __device__ const ColsT COLS = mkCols();   // rodata, uniform s_load

// ---- workspace layout (f2 units) -- TOTAL 864 f2 = 6912 B ----
// [0,288)    RY triples: layer l, wire w -> {c,c},{-s,-s},{s,s}
// [288,544)  kfacP: Dphi  per-k  (k = amp bits 0..3, wire 11-j)
// [544,800)  kfacW: Domega per-k' (k' = amp bits 6..9, wire 5-j)
// [800,864)  angs:  f2{angP, angW} lane-bit half-angles
//            angP: g bit j <-> amp 4+j <-> wire 7-j (canonical)
//            angW: g bit j <-> amp {10,11,0,1,2,3,4,5}[j]
//                  <-> wire {1,0,11,10,9,8,7,6}[j]   (phase-B layout)
// (Identical to R9's tables -- correctness-proven by R9's pass.)
#define OFF_KP 288
#define OFF_KW 544
#define OFF_AN 800

__global__ void setup_kernel(const float* __restrict__ wts, f2* __restrict__ mg)
{
    const int t = threadIdx.x;                    // 0..255
    if (t < QDEPTH * WIRES) {
        float th = tanhf(wts[t * 3 + 1]);
        float c = cosf(0.5f * th), s = sinf(0.5f * th);
        mg[(t / 12) * 36 + (t % 12) * 3 + 0] = f2{ c,  c};
        mg[(t / 12) * 36 + (t % 12) * 3 + 1] = f2{-s, -s};
        mg[(t / 12) * 36 + (t % 12) * 3 + 2] = f2{ s,  s};
    }
    if (t < 64) {
        int l = t >> 3, j = t & 7;
        float aP = 0.5f * tanhf(wts[(l * 12 + (7 - j)) * 3 + 0]);
        int wj = (j == 0) ? 1 : (j == 1) ? 0 : (13 - j);
        float aW = 0.5f * tanhf(wts[(l * 12 + wj) * 3 + 2]);
        mg[OFF_AN + l * 8 + j] = f2{aP, aW};
    }
    {
        int l = t >> 5, k = (t >> 1) & 15;
        bool isW = (t & 1) != 0;
        float ph = 0.f;
        #pragma unroll
        for (int j = 0; j < 4; ++j) {
            int wire = isW ? (5 - j) : (11 - j);
            int comp = isW ? 2 : 0;
            float a  = 0.5f * tanhf(wts[(l * 12 + wire) * 3 + comp]);
            ph += ((k >> j) & 1) ? a : -a;
        }
        float s, c;
        sincosf(ph, &s, &c);
        int base = isW ? OFF_KW : OFF_KP;
        mg[base + l * 32 + k * 2 + 0] = f2{ c, c};
        mg[base + l * 32 + k * 2 + 1] = f2{-s, s};
    }
}

// ---- real RY gate on reg bit P: two pairs per asm, 8 pk, chains 4 apart ----
template<int P>
__device__ __forceinline__ void gateR(f2 r[PER_T], f2 cc, f2 ms, f2 ss)
{
    #pragma unroll
    for (int pr = 0; pr < PER_T / 2; pr += 2) {
        const int k0 = ((pr >> P) << (P + 1)) | (pr & ((1 << P) - 1));
        const int k1 = k0 | (1 << P);
        const int q  = pr + 1;
        const int j0 = ((q >> P) << (P + 1)) | (q & ((1 << P) - 1));
        const int j1 = j0 | (1 << P);
        f2 a0, b0, a1, b1;
        asm("v_pk_mul_f32 %0, %4, %8\n\t"
            "v_pk_mul_f32 %1, %4, %10\n\t"
            "v_pk_mul_f32 %2, %6, %8\n\t"
            "v_pk_mul_f32 %3, %6, %10\n\t"
            "v_pk_fma_f32 %0, %5, %9, %0\n\t"
            "v_pk_fma_f32 %1, %5, %8, %1\n\t"
            "v_pk_fma_f32 %2, %7, %9, %2\n\t"
            "v_pk_fma_f32 %3, %7, %8, %3"
            : "=&v"(a0), "=&v"(b0), "=&v"(a1), "=&v"(b1)
            : "v"(r[k0]), "v"(r[k1]), "v"(r[j0]), "v"(r[j1]),
              "v"(cc), "v"(ms), "v"(ss));
        r[k0] = a0; r[k1] = b0; r[j0] = a1; r[j1] = b1;
    }
}

// Cross-lane partner fetch (DPP, VALU pipe, proven R4/R9).
// 0xB1 = quad_perm:[1,0,3,2] = lane^1; 0x4E = [2,3,0,1] = lane^2.
template<int CTRL>
__device__ __forceinline__ f2 dpp_xor(f2 v) {
    f2 o;
    o.x = __int_as_float(__builtin_amdgcn_update_dpp(
            0, __float_as_int(v.x), CTRL, 0xF, 0xF, true));
    o.y = __int_as_float(__builtin_amdgcn_update_dpp(
            0, __float_as_int(v.y), CTRL, 0xF, 0xF, true));
    return o;
}

// Real RY gate on a DPP lane bit: out = cc*self + k2*partner,
// k2 = (lane bit set) ? ss : ms.  (Proven R9.)
template<int CTRL>
__device__ __forceinline__ void dgateR(f2 r[PER_T], f2 cc, f2 k2)
{
    #pragma unroll
    for (int k0 = 0; k0 < PER_T; k0 += 4) {
        f2 p0 = dpp_xor<CTRL>(r[k0 + 0]);
        f2 p1 = dpp_xor<CTRL>(r[k0 + 1]);
        f2 p2 = dpp_xor<CTRL>(r[k0 + 2]);
        f2 p3 = dpp_xor<CTRL>(r[k0 + 3]);
        f2 o0, o1, o2, o3;
        asm("v_pk_mul_f32 %0, %4, %12\n\t"
            "v_pk_mul_f32 %1, %5, %12\n\t"
            "v_pk_mul_f32 %2, %6, %12\n\t"
            "v_pk_mul_f32 %3, %7, %12\n\t"
            "v_pk_fma_f32 %0, %8, %13, %0\n\t"
            "v_pk_fma_f32 %1, %9, %13, %1\n\t"
            "v_pk_fma_f32 %2, %10, %13, %2\n\t"
            "v_pk_fma_f32 %3, %11, %13, %3"
            : "=&v"(o0), "=&v"(o1), "=&v"(o2), "=&v"(o3)
            : "v"(r[k0]), "v"(r[k0+1]), "v"(r[k0+2]), "v"(r[k0+3]),
              "v"(p0), "v"(p1), "v"(p2), "v"(p3),
              "v"(cc), "v"(k2));
        r[k0] = o0; r[k0+1] = o1; r[k0+2] = o2; r[k0+3] = o3;
    }
}

// Complex diag multiply on two regs (proven op_sel pattern, R8).
__device__ __forceinline__ void dmul2(f2& a0, f2& a1, f2 d0r, f2 d0w,
                                      f2 d1r, f2 d1w)
{
    f2 o0, o1;
    asm("v_pk_mul_f32 %0, %2, %4\n\t"
        "v_pk_mul_f32 %1, %3, %6\n\t"
        "v_pk_fma_f32 %0, %2, %5, %0 op_sel:[1,0,0] op_sel_hi:[0,1,1]\n\t"
        "v_pk_fma_f32 %1, %3, %7, %1 op_sel:[1,0,0] op_sel_hi:[0,1,1]"
        : "=&v"(o0), "=&v"(o1)
        : "v"(a0), "v"(a1), "v"(d0r), "v"(d0w), "v"(d1r), "v"(d1w));
    a0 = o0; a1 = o1;
}

// Tensor-product diagonal (R8-proven; sincosf -> fast __sinf/__cosf,
// |ph| <= 4 rad so no range-reduction issues).
__device__ __forceinline__ void diag(f2 r[PER_T], const f2* __restrict__ AN,
                                     const f2* __restrict__ KF, int g, bool isW)
{
    float ph = 0.f;
    #pragma unroll
    for (int j = 0; j < 8; ++j) {
        float a = isW ? AN[j].y : AN[j].x;
        ph += ((g >> j) & 1) ? a : -a;
    }
    float s = __sinf(ph), c = __cosf(ph);
    const f2 Lr = f2{c, c}, Lw = f2{-s, s};
    #pragma unroll
    for (int k = 0; k < PER_T; k += 2)
        dmul2(r[k], r[k + 1], Lr, Lw, Lr, Lw);
    #pragma unroll
    for (int k = 0; k < PER_T; k += 2)
        dmul2(r[k], r[k + 1], KF[2*k], KF[2*k + 1], KF[2*k + 2], KF[2*k + 3]);
}

// 4 waves = one batch element. Canonical: r[k] = amp[(g<<4)|k].
// Per layer (U = P . Domega . Y . Dphi), R9 schedule on R8 layout:
//   Dphi ; phase A: RY wires 11..8 (reg bits) + 7,6 (lane bits 0,1 DPP)
//   W1 pad-17 canonical -> barrier -> R1 phase-B layout:
//     regs <- amp 6..9, lane0,1 <- amp 10,11, lane2..7 <- amp 0..5
//     slot = slotf(base_g) + 68k  (additivity exact; 4 lanes/bank-pair)
//   phase B: RY wires 5..2 (regs) + 1,0 (lane bits 0,1 DPP) ; Domega
//   W2 same slots (no barrier vs R1: lane-private set) -> barrier ->
//   RF: F-gather back to canonical (R8 verbatim) -> barrier
// 3 barriers/layer; 64 b64 LDS ops/wave/layer (vs R8's 96).
__global__ __launch_bounds__(BLOCK, 4) void qsim_kernel(
    const float* __restrict__ x,
    const f2*    __restrict__ mg,
    const int*   __restrict__ reps_ptr,
    float*       __restrict__ out,
    int write_mode)
{
    __shared__ f2 st[4352];                          // 34816 B -> 4 blocks/CU

    const int g = threadIdx.x;
    const int b = blockIdx.x;
    const bool hb0 = (g & 1) != 0;   // lane bit 0 value
    const bool hb1 = (g & 2) != 0;   // lane bit 1 value

    const int w1b = 17 * g;          // W1: slot((g<<4)|k) = 17g + k
    // R1/W2: base_g = amp{11:10}=g{1:0}, amp{5:0}=g{7:2}; slot = slotf(base_g)+68k
    const int base_g = ((g & 3) << 10) | (g >> 2);
    const int rAb    = base_g + (base_g >> 4);       // slotf(base_g)

    // ---- load: lane g holds amps (g<<4)|k, k=0..15 (64B contiguous) ----
    const float4* xb4 = (const float4*)(x + (size_t)b * NSTATE) + g * 4;
    f2 r[PER_T];
    #pragma unroll
    for (int c = 0; c < 4; ++c) {
        float4 v = xb4[c];
        r[4*c+0] = f2{v.x, 0.f};
        r[4*c+1] = f2{v.y, 0.f};
        r[4*c+2] = f2{v.z, 0.f};
        r[4*c+3] = f2{v.w, 0.f};
    }

    const int reps = reps_ptr[0];
    for (int rep = 0; rep < reps; ++rep) {
        #pragma unroll 1
        for (int l = 0; l < QDEPTH; ++l) {
            const f2* CS = mg + l * 36;
            const f2* KP = mg + OFF_KP + l * 32;
            const f2* KW = mg + OFF_KW + l * 32;
            const f2* AN = mg + OFF_AN + l * 8;

            // Dphi (canonical layout)
            diag(r, AN, KP, g, false);

            // phase A: wires 11..8 on reg bits 0..3, wires 7,6 on lanes
            gateR<0>(r, CS[11*3], CS[11*3+1], CS[11*3+2]);
            gateR<1>(r, CS[10*3], CS[10*3+1], CS[10*3+2]);
            gateR<2>(r, CS[9*3],  CS[9*3+1],  CS[9*3+2]);
            gateR<3>(r, CS[8*3],  CS[8*3+1],  CS[8*3+2]);
            dgateR<0xB1>(r, CS[7*3], hb0 ? CS[7*3+2] : CS[7*3+1]);
            dgateR<0x4E>(r, CS[6*3], hb1 ? CS[6*3+2] : CS[6*3+1]);

            // W1: scatter canonical, pad-17 (base + imm)
            #pragma unroll
            for (int k = 0; k < PER_T; ++k) st[w1b + k] = r[k];
            __syncthreads();

            // R1: gather phase-B layout (base + 68k imm)
            #pragma unroll
            for (int k = 0; k < PER_T; ++k) r[k] = st[rAb + 68 * k];
            // no barrier: W2 rewrites exactly the slots this lane read

            // phase B: wires 5..2 on reg bits 0..3, wires 1,0 on lanes
            gateR<0>(r, CS[5*3], CS[5*3+1], CS[5*3+2]);
            gateR<1>(r, CS[4*3], CS[4*3+1], CS[4*3+2]);
            gateR<2>(r, CS[3*3], CS[3*3+1], CS[3*3+2]);
            gateR<3>(r, CS[2*3], CS[2*3+1], CS[2*3+2]);
            dgateR<0xB1>(r, CS[1*3], hb0 ? CS[1*3+2] : CS[1*3+1]);
            dgateR<0x4E>(r, CS[0*3], hb1 ? CS[0*3+2] : CS[0*3+1]);

            // Domega (phase-B layout tensor diag)
            diag(r, AN, KW, g, true);

            // W2: store back to the same slots
            #pragma unroll
            for (int k = 0; k < PER_T; ++k) st[rAb + 68 * k] = r[k];
            __syncthreads();

            // RF: F-gather back to canonical (R8 verbatim, pad-17)
            {
                int Fg = 0;
                #pragma unroll
                for (int j = 0; j < 8; ++j)
                    Fg ^= ((g >> j) & 1) ? COLS.v[l][4 + j] : 0;
                const int c0 = COLS.v[l][0], c1 = COLS.v[l][1];
                const int c2 = COLS.v[l][2], c3 = COLS.v[l][3];
                #pragma unroll
                for (int k = 0; k < PER_T; ++k) {
                    int ck = ((k & 1) ? c0 : 0) ^ ((k & 2) ? c1 : 0) ^
                             ((k & 4) ? c2 : 0) ^ ((k & 8) ? c3 : 0);
                    r[k] = st[slotf(Fg ^ ck)];
                }
            }
            __syncthreads();   // drain F reads before next layer's W1
        }
    }

    // ---- write out (r is canonical: 16 consecutive amps per lane) ----
    if (write_mode == 0) {
        // harness views complex output as float32 real part
        float4* ob4 = (float4*)(out + (size_t)b * NSTATE) + g * 4;
        #pragma unroll
        for (int c = 0; c < 4; ++c)
            ob4[c] = make_float4(r[4*c].x, r[4*c+1].x, r[4*c+2].x, r[4*c+3].x);
    } else {
        float4* ob4 = (float4*)((float2*)out + (size_t)b * NSTATE) + g * 8;
        #pragma unroll
        for (int k = 0; k < PER_T; k += 2)
            ob4[k >> 1] = make_float4(r[k].x, r[k].y, r[k+1].x, r[k+1].y);
    }
}

extern "C" void kernel_launch(void* const* d_in, const int* in_sizes, int n_in,
                              void* d_out, int out_size, void* d_ws, size_t ws_size,
                              hipStream_t stream) {
    const float* x    = (const float*)d_in[0];
    const float* wts  = (const float*)d_in[1];
    const int*   reps = (const int*)d_in[2];
    float*       out  = (float*)d_out;
    f2*          mg   = (f2*)d_ws;            // 864 f2 = 6912 B scratch
    (void)in_sizes; (void)n_in; (void)ws_size;

    const int write_mode = (out_size >= 2 * 1024 * NSTATE) ? 1 : 0;

    setup_kernel<<<1, 256, 0, stream>>>(wts, mg);
    qsim_kernel<<<1024, BLOCK, 0, stream>>>(x, mg, reps, out, write_mode);
}

// Round 11
// 138.398 us; speedup vs baseline: 1.0112x; 1.0112x over previous
//
#include <hip/hip_runtime.h>

#define WIRES   12
#define NSTATE  4096          // 2^12
#define QDEPTH  8
#define BLOCK   256           // 4 waves per block = one batch element
#define PER_T   16            // 4 reg bits; +2 quad-DPP lane bits = 6 wires/phase

using f2 = __attribute__((ext_vector_type(2))) float;

// 3-nibble additive pad: amp a -> f2-slot a + (a>>4) + (a>>8).
// Unlike pad-17, amp bits 8..11 reach the bank hash (slot%16 = sum of
// nibbles), so phase-B transposes with amp10,11 on lane bits 0,1 are
// conflict-free per 32-lane group (enumerated: exactly 2 lanes/bank-pair
// for W1 and R1/W2). Bijective (monotone). Max slot 4365.
__device__ __forceinline__ int slotf3(int a) { return a + (a >> 4) + (a >> 8); }

// Column j of the GF(2)-linear CNOT-ring permutation of layer l:
// F = g_0∘g_1∘...∘g_11 (g_11 applied first / innermost).
constexpr int colF(int l, int j) {
    int rr = (l % (WIRES - 1)) + 1;
    int v = 1 << j;
    for (int k = WIRES - 1; k >= 0; --k) {
        int bc = 11 - k;                   // control bit
        int bt = 11 - ((k + rr) % WIRES);  // target bit
        v ^= ((v >> bc) & 1) << bt;
    }
    return v;
}
struct ColsT { int v[QDEPTH][WIRES]; };
constexpr ColsT mkCols() {
    ColsT c{};
    for (int l = 0; l < QDEPTH; ++l)
        for (int j = 0; j < WIRES; ++j) c.v[l][j] = colF(l, j);
    return c;
}
static __device__ const ColsT COLS = mkCols();   // rodata, uniform s_load

// ---- workspace layout (f2 units) -- TOTAL 864 f2 = 6912 B ----
// [0,288)    RY triples: layer l, wire w -> {c,c},{-s,-s},{s,s}
// [288,544)  kfacP: Dphi  per-k  (k = amp bits 0..3, wire 11-j)
// [544,800)  kfacW: Domega per-k' (k' = amp bits 6..9, wire 5-j)
// [800,864)  angs:  f2{angP, angW} lane-bit half-angles
//            angP: g bit j <-> amp 4+j <-> wire 7-j (canonical)
//            angW: g bit j <-> amp {10,11,0,1,2,3,4,5}[j]
//                  <-> wire {1,0,11,10,9,8,7,6}[j]   (phase-B layout)
// (Identical to R9/R10's tables -- correctness-proven twice.)
#define OFF_KP 288
#define OFF_KW 544
#define OFF_AN 800

__global__ void setup_kernel(const float* __restrict__ wts, f2* __restrict__ mg)
{
    const int t = threadIdx.x;                    // 0..255
    if (t < QDEPTH * WIRES) {
        float th = tanhf(wts[t * 3 + 1]);
        float c = cosf(0.5f * th), s = sinf(0.5f * th);
        mg[(t / 12) * 36 + (t % 12) * 3 + 0] = f2{ c,  c};
        mg[(t / 12) * 36 + (t % 12) * 3 + 1] = f2{-s, -s};
        mg[(t / 12) * 36 + (t % 12) * 3 + 2] = f2{ s,  s};
    }
    if (t < 64) {
        int l = t >> 3, j = t & 7;
        float aP = 0.5f * tanhf(wts[(l * 12 + (7 - j)) * 3 + 0]);
        int wj = (j == 0) ? 1 : (j == 1) ? 0 : (13 - j);
        float aW = 0.5f * tanhf(wts[(l * 12 + wj) * 3 + 2]);
        mg[OFF_AN + l * 8 + j] = f2{aP, aW};
    }
    {
        int l = t >> 5, k = (t >> 1) & 15;
        bool isW = (t & 1) != 0;
        float ph = 0.f;
        #pragma unroll
        for (int j = 0; j < 4; ++j) {
            int wire = isW ? (5 - j) : (11 - j);
            int comp = isW ? 2 : 0;
            float a  = 0.5f * tanhf(wts[(l * 12 + wire) * 3 + comp]);
            ph += ((k >> j) & 1) ? a : -a;
        }
        float s, c;
        sincosf(ph, &s, &c);
        int base = isW ? OFF_KW : OFF_KP;
        mg[base + l * 32 + k * 2 + 0] = f2{ c, c};
        mg[base + l * 32 + k * 2 + 1] = f2{-s, s};
    }
}

// ---- real RY gate on reg bit P: two pairs per asm, 8 pk, chains 4 apart ----
template<int P>
__device__ __forceinline__ void gateR(f2 r[PER_T], f2 cc, f2 ms, f2 ss)
{
    #pragma unroll
    for (int pr = 0; pr < PER_T / 2; pr += 2) {
        const int k0 = ((pr >> P) << (P + 1)) | (pr & ((1 << P) - 1));
        const int k1 = k0 | (1 << P);
        const int q  = pr + 1;
        const int j0 = ((q >> P) << (P + 1)) | (q & ((1 << P) - 1));
        const int j1 = j0 | (1 << P);
        f2 a0, b0, a1, b1;
        asm("v_pk_mul_f32 %0, %4, %8\n\t"
            "v_pk_mul_f32 %1, %4, %10\n\t"
            "v_pk_mul_f32 %2, %6, %8\n\t"
            "v_pk_mul_f32 %3, %6, %10\n\t"
            "v_pk_fma_f32 %0, %5, %9, %0\n\t"
            "v_pk_fma_f32 %1, %5, %8, %1\n\t"
            "v_pk_fma_f32 %2, %7, %9, %2\n\t"
            "v_pk_fma_f32 %3, %7, %8, %3"
            : "=&v"(a0), "=&v"(b0), "=&v"(a1), "=&v"(b1)
            : "v"(r[k0]), "v"(r[k1]), "v"(r[j0]), "v"(r[j1]),
              "v"(cc), "v"(ms), "v"(ss));
        r[k0] = a0; r[k1] = b0; r[j0] = a1; r[j1] = b1;
    }
}

// Cross-lane partner fetch (DPP, VALU pipe, proven R4/R9/R10).
// 0xB1 = quad_perm:[1,0,3,2] = lane^1; 0x4E = [2,3,0,1] = lane^2.
template<int CTRL>
__device__ __forceinline__ f2 dpp_xor(f2 v) {
    f2 o;
    o.x = __int_as_float(__builtin_amdgcn_update_dpp(
            0, __float_as_int(v.x), CTRL, 0xF, 0xF, true));
    o.y = __int_as_float(__builtin_amdgcn_update_dpp(
            0, __float_as_int(v.y), CTRL, 0xF, 0xF, true));
    return o;
}

// Real RY gate on a DPP lane bit: out = cc*self + k2*partner,
// k2 = (lane bit set) ? ss : ms.  (Proven R9/R10.)
template<int CTRL>
__device__ __forceinline__ void dgateR(f2 r[PER_T], f2 cc, f2 k2)
{
    #pragma unroll
    for (int k0 = 0; k0 < PER_T; k0 += 4) {
        f2 p0 = dpp_xor<CTRL>(r[k0 + 0]);
        f2 p1 = dpp_xor<CTRL>(r[k0 + 1]);
        f2 p2 = dpp_xor<CTRL>(r[k0 + 2]);
        f2 p3 = dpp_xor<CTRL>(r[k0 + 3]);
        f2 o0, o1, o2, o3;
        asm("v_pk_mul_f32 %0, %4, %12\n\t"
            "v_pk_mul_f32 %1, %5, %12\n\t"
            "v_pk_mul_f32 %2, %6, %12\n\t"
            "v_pk_mul_f32 %3, %7, %12\n\t"
            "v_pk_fma_f32 %0, %8, %13, %0\n\t"
            "v_pk_fma_f32 %1, %9, %13, %1\n\t"
            "v_pk_fma_f32 %2, %10, %13, %2\n\t"
            "v_pk_fma_f32 %3, %11, %13, %3"
            : "=&v"(o0), "=&v"(o1), "=&v"(o2), "=&v"(o3)
            : "v"(r[k0]), "v"(r[k0+1]), "v"(r[k0+2]), "v"(r[k0+3]),
              "v"(p0), "v"(p1), "v"(p2), "v"(p3),
              "v"(cc), "v"(k2));
        r[k0] = o0; r[k0+1] = o1; r[k0+2] = o2; r[k0+3] = o3;
    }
}

// Complex diag multiply on two regs (proven op_sel pattern, R8).
__device__ __forceinline__ void dmul2(f2& a0, f2& a1, f2 d0r, f2 d0w,
                                      f2 d1r, f2 d1w)
{
    f2 o0, o1;
    asm("v_pk_mul_f32 %0, %2, %4\n\t"
        "v_pk_mul_f32 %1, %3, %6\n\t"
        "v_pk_fma_f32 %0, %2, %5, %0 op_sel:[1,0,0] op_sel_hi:[0,1,1]\n\t"
        "v_pk_fma_f32 %1, %3, %7, %1 op_sel:[1,0,0] op_sel_hi:[0,1,1]"
        : "=&v"(o0), "=&v"(o1)
        : "v"(a0), "v"(a1), "v"(d0r), "v"(d0w), "v"(d1r), "v"(d1w));
    a0 = o0; a1 = o1;
}

// Tensor-product diagonal (proven R8/R10): per-lane fast sincos +
// wave-uniform per-k factors. |ph| <= 4 rad -> fast path safe.
__device__ __forceinline__ void diag(f2 r[PER_T], const f2* __restrict__ AN,
                                     const f2* __restrict__ KF, int g, bool isW)
{
    float ph = 0.f;
    #pragma unroll
    for (int j = 0; j < 8; ++j) {
        float a = isW ? AN[j].y : AN[j].x;
        ph += ((g >> j) & 1) ? a : -a;
    }
    float s = __sinf(ph), c = __cosf(ph);
    const f2 Lr = f2{c, c}, Lw = f2{-s, s};
    #pragma unroll
    for (int k = 0; k < PER_T; k += 2)
        dmul2(r[k], r[k + 1], Lr, Lw, Lr, Lw);
    #pragma unroll
    for (int k = 0; k < PER_T; k += 2)
        dmul2(r[k], r[k + 1], KF[2*k], KF[2*k + 1], KF[2*k + 2], KF[2*k + 3]);
}

// 4 waves = one batch element. Canonical: r[k] = amp[(g<<4)|k].
// R10 schedule (correctness-proven), slotf3 layout (bank-verified):
//   Dphi ; phase A: RY wires 11..8 (reg bits) + 7,6 (lane bits 0,1 DPP)
//   W1 slot = 17g+(g>>4)+k [free] -> barrier -> R1 phase-B layout:
//     regs <- amp 6..9, lane0,1 <- amp 10,11, lane2..7 <- amp 0..5
//     slot = slotf3(base_g) + 68k + (k>>2)  [additivity exact; free]
//   phase B: RY wires 5..2 (regs) + 1,0 (lane bits 0,1 DPP) ; Domega
//   W2 same slots (no barrier vs R1: lane-private set) -> barrier ->
//   RF: F-gather back to canonical, slot = slotf3(Fg^ck) -> barrier
// 3 barriers/layer; 64 b64 LDS ops/wave/layer.
__global__ __launch_bounds__(BLOCK, 4) void qsim_kernel(
    const float* __restrict__ x,
    const f2*    __restrict__ mg,
    const int*   __restrict__ reps_ptr,
    float*       __restrict__ out,
    int write_mode)
{
    __shared__ f2 st[4366];                          // 34928 B -> 4 blocks/CU

    const int g = threadIdx.x;
    const int b = blockIdx.x;
    const bool hb0 = (g & 1) != 0;   // lane bit 0 value
    const bool hb1 = (g & 2) != 0;   // lane bit 1 value

    const int w1b = 17 * g + (g >> 4);   // W1: slotf3((g<<4)|k) = w1b + k
    // R1/W2: base_g = amp{11:10}=g{1:0}, amp{5:0}=g{7:2}
    // slot = slotf3(base_g) + 68k + (k>>2)  (disjoint-field additivity)
    const int base_g = ((g & 3) << 10) | (g >> 2);
    const int rAb    = base_g + (base_g >> 4) + (base_g >> 8);

    // ---- load: lane g holds amps (g<<4)|k, k=0..15 (64B contiguous) ----
    const float4* xb4 = (const float4*)(x + (size_t)b * NSTATE) + g * 4;
    f2 r[PER_T];
    #pragma unroll
    for (int c = 0; c < 4; ++c) {
        float4 v = xb4[c];
        r[4*c+0] = f2{v.x, 0.f};
        r[4*c+1] = f2{v.y, 0.f};
        r[4*c+2] = f2{v.z, 0.f};
        r[4*c+3] = f2{v.w, 0.f};
    }

    const int reps = reps_ptr[0];
    for (int rep = 0; rep < reps; ++rep) {
        #pragma unroll 1
        for (int l = 0; l < QDEPTH; ++l) {
            const f2* CS = mg + l * 36;
            const f2* KP = mg + OFF_KP + l * 32;
            const f2* KW = mg + OFF_KW + l * 32;
            const f2* AN = mg + OFF_AN + l * 8;

            // Dphi (canonical layout)
            diag(r, AN, KP, g, false);

            // phase A: wires 11..8 on reg bits 0..3, wires 7,6 on lanes
            gateR<0>(r, CS[11*3], CS[11*3+1], CS[11*3+2]);
            gateR<1>(r, CS[10*3], CS[10*3+1], CS[10*3+2]);
            gateR<2>(r, CS[9*3],  CS[9*3+1],  CS[9*3+2]);
            gateR<3>(r, CS[8*3],  CS[8*3+1],  CS[8*3+2]);
            dgateR<0xB1>(r, CS[7*3], hb0 ? CS[7*3+2] : CS[7*3+1]);
            dgateR<0x4E>(r, CS[6*3], hb1 ? CS[6*3+2] : CS[6*3+1]);

            // W1: scatter canonical (base + imm; conflict-free)
            #pragma unroll
            for (int k = 0; k < PER_T; ++k) st[w1b + k] = r[k];
            __syncthreads();

            // R1: gather phase-B layout (base + imm; conflict-free)
            #pragma unroll
            for (int k = 0; k < PER_T; ++k)
                r[k] = st[rAb + 68 * k + (k >> 2)];
            // no barrier: W2 rewrites exactly the slots this lane read

            // phase B: wires 5..2 on reg bits 0..3, wires 1,0 on lanes
            gateR<0>(r, CS[5*3], CS[5*3+1], CS[5*3+2]);
            gateR<1>(r, CS[4*3], CS[4*3+1], CS[4*3+2]);
            gateR<2>(r, CS[3*3], CS[3*3+1], CS[3*3+2]);
            gateR<3>(r, CS[2*3], CS[2*3+1], CS[2*3+2]);
            dgateR<0xB1>(r, CS[1*3], hb0 ? CS[1*3+2] : CS[1*3+1]);
            dgateR<0x4E>(r, CS[0*3], hb1 ? CS[0*3+2] : CS[0*3+1]);

            // Domega (phase-B layout tensor diag)
            diag(r, AN, KW, g, true);

            // W2: store back to the same slots
            #pragma unroll
            for (int k = 0; k < PER_T; ++k)
                st[rAb + 68 * k + (k >> 2)] = r[k];
            __syncthreads();

            // RF: F-gather back to canonical (slotf3 hash)
            {
                int Fg = 0;
                #pragma unroll
                for (int j = 0; j < 8; ++j)
                    Fg ^= ((g >> j) & 1) ? COLS.v[l][4 + j] : 0;
                const int c0 = COLS.v[l][0], c1 = COLS.v[l][1];
                const int c2 = COLS.v[l][2], c3 = COLS.v[l][3];
                #pragma unroll
                for (int k = 0; k < PER_T; ++k) {
                    int ck = ((k & 1) ? c0 : 0) ^ ((k & 2) ? c1 : 0) ^
                             ((k & 4) ? c2 : 0) ^ ((k & 8) ? c3 : 0);
                    int a  = Fg ^ ck;
                    r[k] = st[a + (a >> 4) + (a >> 8)];
                }
            }
            __syncthreads();   // drain F reads before next layer's W1
        }
    }

    // ---- write out (r is canonical: 16 consecutive amps per lane) ----
    if (write_mode == 0) {
        // harness views complex output as float32 real part
        float4* ob4 = (float4*)(out + (size_t)b * NSTATE) + g * 4;
        #pragma unroll
        for (int c = 0; c < 4; ++c)
            ob4[c] = make_float4(r[4*c].x, r[4*c+1].x, r[4*c+2].x, r[4*c+3].x);
    } else {
        float4* ob4 = (float4*)((float2*)out + (size_t)b * NSTATE) + g * 8;
        #pragma unroll
        for (int k = 0; k < PER_T; k += 2)
            ob4[k >> 1] = make_float4(r[k].x, r[k].y, r[k+1].x, r[k+1].y);
    }
}

extern "C" void kernel_launch(void* const* d_in, const int* in_sizes, int n_in,
                              void* d_out, int out_size, void* d_ws, size_t ws_size,
                              hipStream_t stream) {
    const float* x    = (const float*)d_in[0];
    const float* wts  = (const float*)d_in[1];
    const int*   reps = (const int*)d_in[2];
    float*       out  = (float*)d_out;
    f2*          mg   = (f2*)d_ws;            // 864 f2 = 6912 B scratch
    (void)in_sizes; (void)n_in; (void)ws_size;

    const int write_mode = (out_size >= 2 * 1024 * NSTATE) ? 1 : 0;

    setup_kernel<<<1, 256, 0, stream>>>(wts, mg);
    qsim_kernel<<<1024, BLOCK, 0, stream>>>(x, mg, reps, out, write_mode);
}